// Round 18
// baseline (347.646 us; speedup 1.0000x reference)
//
#include <hip/hip_runtime.h>
#include <cstdint>
#include <cstddef>

#define T_ 256
#define HN_ 4096
#define H_ 32
#define N_ 128
#define SR_ 6464   // COMB row stride (4096 R + 1024 K + 1024 V + 320 T)

typedef __attribute__((ext_vector_type(8))) short short8;
typedef __attribute__((ext_vector_type(4))) float f32x4;

__device__ __forceinline__ short f2bf(float f) {
    uint32_t u = __builtin_bit_cast(uint32_t, f);
    u = (u + 0x7fffu + ((u >> 16) & 1u)) >> 16;   // RNE f32->bf16
    return (short)u;
}
__device__ __forceinline__ short f2bfc(float f) {  // cheap round-half-up
    return (short)((__builtin_bit_cast(uint32_t, f) + 0x8000u) >> 16);
}
__device__ __forceinline__ short8 cvt8r(float4 lo, float4 hi) {
    short8 v;
    v[0] = f2bfc(lo.x); v[1] = f2bfc(lo.y); v[2] = f2bfc(lo.z); v[3] = f2bfc(lo.w);
    v[4] = f2bfc(hi.x); v[5] = f2bfc(hi.y); v[6] = f2bfc(hi.z); v[7] = f2bfc(hi.w);
    return v;
}
__device__ __forceinline__ f32x4 mfma16(short8 a, short8 b, f32x4 c) {
    return __builtin_amdgcn_mfma_f32_16x16x32_bf16(a, b, c, 0, 0, 0);
}
__device__ __forceinline__ float sigm(float x) { return 1.f / (1.f + expf(-x)); }
__device__ __forceinline__ float splus(float x) { return (x > 20.f) ? x : log1pf(expf(x)); }

__device__ __forceinline__ float bf1(ushort u) {
    return __builtin_bit_cast(float, (uint32_t)u << 16);
}

// ---- DPP cross-lane add (VALU pipe) --------------------------------------------
template <int CTRL>
__device__ __forceinline__ float dpp_add(float v) {
    int p = __builtin_amdgcn_mov_dpp(__builtin_bit_cast(int, v), CTRL, 0xF, 0xF, true);
    return v + __builtin_bit_cast(float, p);
}
// Full 64-lane reduce -> uniform scalar (DS-free; verified R12)
__device__ __forceinline__ float reduce64(float v) {
    v = dpp_add<0xB1>(v);     // quad_perm [1,0,3,2]  (xor 1)
    v = dpp_add<0x4E>(v);     // quad_perm [2,3,0,1]  (xor 2)
    v = dpp_add<0x124>(v);    // row_ror:4
    v = dpp_add<0x128>(v);    // row_ror:8
    v = dpp_add<0x142>(v);    // row_bcast:15
    v = dpp_add<0x143>(v);    // row_bcast:31
    int r = __builtin_amdgcn_readlane(__builtin_bit_cast(int, v), 63);
    return __builtin_bit_cast(float, r);
}

// ---- GEMM core v2: B dequantized ONCE per stage into bf16 LDS tile (R16) --------
__device__ __forceinline__ void gemm_core(
    const ushort* __restrict__ A, const float* __restrict__ Brow,
    int kbeg, ushort* LH, f32x4 acc[2][2]) {
    const int tid = threadIdx.x, wid = tid >> 6, l = tid & 63;
    const int ar = l & 15, ak = (l >> 4) * 8;
    const int mBase = wid * 32;

    const int brw = tid >> 4, bc8 = tid & 15;
    const float* bsrc = Brow + (size_t)brw * 4096 + kbeg + bc8 * 8;
    const int hoff = brw * 128 + ((bc8 ^ (brw & 7)) * 8);

    const ushort* pa0 = A + (size_t)(mBase + ar) * 4096 + kbeg + ak;
    const ushort* pa1 = pa0 + (size_t)16 * 4096;

    const int akc = ak >> 3;
    const int sx0 = ar & 7;
    const int rb0 = ar * 128, rb1 = (16 + ar) * 128;

    short8 Ae[8], Ao[8];
    float4 B0a, B0b, B1a, B1b;

#define LB0(s) { B0a = *(const float4*)(bsrc + (size_t)(s) * 128); \
                 B0b = *(const float4*)(bsrc + (size_t)(s) * 128 + 4); }
#define LB1(s) { B1a = *(const float4*)(bsrc + (size_t)(s) * 128); \
                 B1b = *(const float4*)(bsrc + (size_t)(s) * 128 + 4); }

#define LA(B_, s) { \
    B_[0] = *(const short8*)(pa0 + (size_t)(s) * 128);      \
    B_[1] = *(const short8*)(pa1 + (size_t)(s) * 128);      \
    B_[2] = *(const short8*)(pa0 + (size_t)(s) * 128 + 32); \
    B_[3] = *(const short8*)(pa1 + (size_t)(s) * 128 + 32); \
    B_[4] = *(const short8*)(pa0 + (size_t)(s) * 128 + 64); \
    B_[5] = *(const short8*)(pa1 + (size_t)(s) * 128 + 64); \
    B_[6] = *(const short8*)(pa0 + (size_t)(s) * 128 + 96); \
    B_[7] = *(const short8*)(pa1 + (size_t)(s) * 128 + 96); }

#define CKK(kk, B_, Hb_) { \
    const int sl = ((kk) * 4 + akc) ^ sx0; \
    short8 b0 = *(const short8*)((Hb_) + rb0 + sl * 8); \
    short8 b1 = *(const short8*)((Hb_) + rb1 + sl * 8); \
    acc[0][0] = mfma16(B_[2 * (kk)], b0, acc[0][0]); \
    acc[0][1] = mfma16(B_[2 * (kk)], b1, acc[0][1]); \
    acc[1][0] = mfma16(B_[2 * (kk) + 1], b0, acc[1][0]); \
    acc[1][1] = mfma16(B_[2 * (kk) + 1], b1, acc[1][1]); }

#define COMPUTE(Hb_, B_) { CKK(0, B_, Hb_) CKK(1, B_, Hb_) CKK(2, B_, Hb_) CKK(3, B_, Hb_) }

    LB0(0)
    LA(Ae, 0)
    LB1(1)

    for (int su = 0; su < 4; su++) {
        const int s0 = su * 2, s1 = su * 2 + 1;

        *(short8*)(LH + hoff) = cvt8r(B0a, B0b);
        LB0((s0 + 2 < 8) ? s0 + 2 : 7)
        LA(Ao, s0 + 1)
        asm volatile("s_waitcnt lgkmcnt(0)" ::: "memory");
        __builtin_amdgcn_s_barrier();
        __builtin_amdgcn_sched_barrier(0);
        COMPUTE(LH, Ae)

        *(short8*)(LH + 4096 + hoff) = cvt8r(B1a, B1b);
        LB1((s1 + 2 < 8) ? s1 + 2 : 7)
        LA(Ae, (s1 + 1 < 8) ? s1 + 1 : 7)
        asm volatile("s_waitcnt lgkmcnt(0)" ::: "memory");
        __builtin_amdgcn_s_barrier();
        __builtin_amdgcn_sched_barrier(0);
        COMPUTE(LH + 4096, Ao)
    }
#undef LB0
#undef LB1
#undef LA
#undef CKK
#undef COMPUTE
}

// ---------------- RMSNorm over 4096; optional f32 out, bf16 out, lastrow ----------
__global__ __launch_bounds__(256) void rmsnorm_k(const float* __restrict__ in,
                                                 const float* __restrict__ w,
                                                 float* __restrict__ outF,
                                                 ushort* __restrict__ outB,
                                                 float* __restrict__ lastrow) {
    int t = blockIdx.x, tid = threadIdx.x;
    const float4* in4 = (const float4*)(in + (size_t)t * HN_);
    const float4* w4 = (const float4*)w;
    float4 v[4]; float ss = 0.f;
#pragma unroll
    for (int q = 0; q < 4; q++) {
        v[q] = in4[q * 256 + tid];
        ss += v[q].x * v[q].x + v[q].y * v[q].y + v[q].z * v[q].z + v[q].w * v[q].w;
    }
#pragma unroll
    for (int o = 32; o; o >>= 1) ss += __shfl_down(ss, o);
    __shared__ float red[4];
    if ((tid & 63) == 0) red[tid >> 6] = ss;
    __syncthreads();
    float tot = red[0] + red[1] + red[2] + red[3];
    float sc = rsqrtf(tot * (1.f / HN_) + 1e-6f);
#pragma unroll
    for (int q = 0; q < 4; q++) {
        float4 wv = w4[q * 256 + tid];
        float4 r;
        r.x = wv.x * v[q].x * sc; r.y = wv.y * v[q].y * sc;
        r.z = wv.z * v[q].z * sc; r.w = wv.w * v[q].w * sc;
        int idx = q * 256 + tid;
        if (outF) ((float4*)(outF + (size_t)t * HN_))[idx] = r;
        if (outB) {
            ushort4 b;
            b.x = (ushort)f2bf(r.x); b.y = (ushort)f2bf(r.y);
            b.z = (ushort)f2bf(r.z); b.w = (ushort)f2bf(r.w);
            ((ushort4*)(outB + (size_t)t * HN_))[idx] = b;
        }
        if (lastrow && t == T_ - 1) ((float4*)lastrow)[idx] = r;
    }
}

// ---------------- fused R/K/V/LoRA1 split-K GEMM, atomic epilogue into COMB ------
__global__ __launch_bounds__(512, 2) void gemm_rkvt(
    const ushort* __restrict__ A,
    const float* __restrict__ Rw, const float* __restrict__ Kw,
    const float* __restrict__ Vw, const float* __restrict__ WT,
    float* __restrict__ COMB) {
    __shared__ __align__(16) ushort LH[8192];
    const int tid = threadIdx.x, wid = tid >> 6, l = tid & 63;
    const int mBase = wid * 32;
    const int nB = blockIdx.x * 32;
    const int kbeg = blockIdx.y * 1024;

    const float* Bp; int brow;
    if (nB < 4096)      { Bp = Rw; brow = nB; }
    else if (nB < 5120) { Bp = Kw; brow = nB - 4096; }
    else if (nB < 6144) { Bp = Vw; brow = nB - 5120; }
    else                { Bp = WT; brow = nB - 6144; }

    f32x4 acc[2][2];
#pragma unroll
    for (int i = 0; i < 2; i++)
#pragma unroll
        for (int j = 0; j < 2; j++) acc[i][j] = f32x4{0.f, 0.f, 0.f, 0.f};

    gemm_core(A, Bp + (size_t)brow * 4096, kbeg, LH, acc);

    const int rl = (l >> 4) * 4, cl = l & 15;
#pragma unroll
    for (int mf = 0; mf < 2; mf++)
#pragma unroll
        for (int nf = 0; nf < 2; nf++)
#pragma unroll
            for (int e = 0; e < 4; e++)
                unsafeAtomicAdd(&COMB[(size_t)(mBase + mf * 16 + rl + e) * SR_ + nB + nf * 16 + cl],
                                acc[mf][nf][e]);
}

// ---------------- O GEMM: xres += YB @ O^T (atomic, split-K) ---------------------
__global__ __launch_bounds__(512, 2) void gemm_o(
    const ushort* __restrict__ A,
    const float* __restrict__ B,
    float* __restrict__ C) {
    __shared__ __align__(16) ushort LH[8192];
    const int tid = threadIdx.x, wid = tid >> 6, l = tid & 63;
    const int mBase = wid * 32;
    const int nB = blockIdx.x * 32;
    const int kbeg = blockIdx.y * 1024;

    f32x4 acc[2][2];
#pragma unroll
    for (int i = 0; i < 2; i++)
#pragma unroll
        for (int j = 0; j < 2; j++) acc[i][j] = f32x4{0.f, 0.f, 0.f, 0.f};

    gemm_core(A, B + (size_t)nB * 4096, kbeg, LH, acc);

    const int rl = (l >> 4) * 4, cl = l & 15;
#pragma unroll
    for (int mf = 0; mf < 2; mf++)
#pragma unroll
        for (int nf = 0; nf < 2; nf++)
#pragma unroll
            for (int e = 0; e < 4; e++)
                unsafeAtomicAdd(&C[(size_t)(mBase + mf * 16 + rl + e) * 4096 + nB + nf * 16 + cl],
                                acc[mf][nf][e]);
}

// ---------------- fused stage-2 LoRA GEMMs (4 segments via blockIdx.y) -----------
__global__ __launch_bounds__(512) void gemm_s2(
    const ushort* __restrict__ TCB,
    const float* __restrict__ w2, const float* __restrict__ a2,
    const float* __restrict__ v2, const float* __restrict__ g2,
    const float* __restrict__ w0, const float* __restrict__ a0,
    const float* __restrict__ v0,
    float* __restrict__ WPRE, float* __restrict__ APRE,
    float* __restrict__ VGPRE, float* __restrict__ GARR) {
    const int z = blockIdx.y;
    int Aoff, K; const float* B; const float* bias; float* out;
    if (z == 0)      { Aoff = 0;   K = 64;  B = w2; bias = w0;      out = WPRE; }
    else if (z == 1) { Aoff = 64;  K = 64;  B = a2; bias = a0;      out = APRE; }
    else if (z == 2) { Aoff = 128; K = 32;  B = v2; bias = v0;      out = VGPRE; }
    else             { Aoff = 160; K = 128; B = g2; bias = nullptr; out = GARR; }

    const int tid = threadIdx.x, wid = tid >> 6, l = tid & 63;
    const int ar = l & 15, ak = (l >> 4) * 8;
    const int mBase = wid * 32;
    const int nB = blockIdx.x * 32;

    f32x4 acc[2][2];
#pragma unroll
    for (int i = 0; i < 2; i++)
#pragma unroll
        for (int j = 0; j < 2; j++) acc[i][j] = f32x4{0.f, 0.f, 0.f, 0.f};

    for (int k0 = 0; k0 < K; k0 += 32) {
        const ushort* pA = TCB + (size_t)(mBase + ar) * 320 + Aoff + k0 + ak;
        short8 av0 = *(const short8*)pA;
        short8 av1 = *(const short8*)(pA + (size_t)16 * 320);
        short8 bv0, bv1;
#pragma unroll
        for (int e = 0; e < 8; e++) {
            bv0[e] = f2bfc(B[(size_t)(k0 + ak + e) * 4096 + nB + ar]);
            bv1[e] = f2bfc(B[(size_t)(k0 + ak + e) * 4096 + nB + 16 + ar]);
        }
        acc[0][0] = mfma16(av0, bv0, acc[0][0]);
        acc[0][1] = mfma16(av0, bv1, acc[0][1]);
        acc[1][0] = mfma16(av1, bv0, acc[1][0]);
        acc[1][1] = mfma16(av1, bv1, acc[1][1]);
    }
    const int rl = (l >> 4) * 4, cl = l & 15;
#pragma unroll
    for (int mf = 0; mf < 2; mf++)
#pragma unroll
        for (int nf = 0; nf < 2; nf++) {
            int col = nB + nf * 16 + cl;
            float bv = bias ? bias[col] : 0.f;
#pragma unroll
            for (int e = 0; e < 4; e++)
                out[(size_t)(mBase + mf * 16 + rl + e) * 4096 + col] = acc[mf][nf][e] + bv;
        }
}

// ---------------- LoRA-A concat-transpose via LDS tiles -> WT[320][4096] ---------
__global__ __launch_bounds__(256) void wcat2_k(const float* __restrict__ w1p,
                                               const float* __restrict__ a1p,
                                               const float* __restrict__ v1p,
                                               const float* __restrict__ g1p,
                                               float* __restrict__ WT) {
    const int kb = blockIdx.x * 64, tile = blockIdx.y;
    const float* src; int ldw, jo, nb, W;
    if (tile == 0)      { src = w1p; ldw = 64;  jo = 0;  nb = 0;   W = 64; }
    else if (tile == 1) { src = a1p; ldw = 64;  jo = 0;  nb = 64;  W = 64; }
    else if (tile == 2) { src = v1p; ldw = 32;  jo = 0;  nb = 128; W = 32; }
    else if (tile == 3) { src = g1p; ldw = 128; jo = 0;  nb = 160; W = 64; }
    else                { src = g1p; ldw = 128; jo = 64; nb = 224; W = 64; }
    __shared__ float lds[64][65];
    const int ti = threadIdx.x & 63, wi = threadIdx.x >> 6;
    if (ti < W)
        for (int i = wi; i < 64; i += 4)
            lds[i][ti] = src[(size_t)(kb + i) * ldw + jo + ti];
    __syncthreads();
    for (int i2 = wi; i2 < W; i2 += 4)
        WT[(size_t)(nb + i2) * 4096 + kb + ti] = lds[ti][i2];
}

// ---------------- init COMB rows with biases -------------------------------------
__global__ __launch_bounds__(256) void init_comb_k(const float* __restrict__ Rb,
                                                   const float* __restrict__ Kb,
                                                   const float* __restrict__ Vb,
                                                   float* __restrict__ COMB) {
    int t = blockIdx.x;
    for (int c = threadIdx.x; c < SR_; c += 256) {
        float b = (c < 4096) ? Rb[c] : (c < 5120) ? Kb[c - 4096]
                : (c < 6144) ? Vb[c - 5120] : 0.f;
        COMB[(size_t)t * SR_ + c] = b;
    }
}

// ---------------- activations on TCAT cols of COMB -> TCB bf16 [256][320] --------
__global__ __launch_bounds__(256) void act_k(const float* __restrict__ COMB,
                                             ushort* __restrict__ TCB) {
    int idx = blockIdx.x * 256 + threadIdx.x;
    if (idx >= 256 * 288) return;
    int t = idx / 288, c = idx % 288;
    float v = COMB[(size_t)t * SR_ + 6144 + c];
    if (c < 64) v = tanhf(v);
    else if (c >= 160) v = sigm(v);
    TCB[t * 320 + c] = (ushort)f2bf(v);
}

// ---------------- prep: pairwise (L=2) scan stream, rope fused (R13) -------------
__global__ __launch_bounds__(256) void prep_k(
    const float* __restrict__ COMB, const float* __restrict__ wpre,
    const float* __restrict__ apre, const float* __restrict__ vgpre,
    const float* __restrict__ vfirst, const float* __restrict__ garr,
    const float* __restrict__ rkg, const int* __restrict__ cpos,
    const float* __restrict__ lnr, const float* __restrict__ lnk,
    ushort* __restrict__ SFB) {
    const int tp = blockIdx.x, hg = blockIdx.y;
    const int tid = threadIdx.x;
    const int w = tid >> 6, lane = tid & 63;
    const int t0 = tp * 2, t1 = t0 + 1;

    float e = (float)lane * (1.f / 64.f);
    float inv_s = exp2f(-13.287712379549449f * e);
    float inv_l = exp2f(-13.287712379549449f - 3.321928094887362f * e);
    float base = (float)cpos[0];
    float pos0 = base + (float)t0, pos1 = base + (float)t1;
    float mix0 = fminf(fmaxf(pos0 * (1.f / 4096.f), 0.f), 1.f);
    float mix1 = fminf(fmaxf(pos1 * (1.f / 4096.f), 0.f), 1.f);
    float fr0 = pos0 * ((1.f - mix0) * inv_s + mix0 * inv_l);
    float fr1 = pos1 * ((1.f - mix1) * inv_s + mix1 * inv_l);
    float cA = cosf(fr0), sA = sinf(fr0);
    float cB = cosf(fr1), sB = sinf(fr1);

    float lr0 = lnr[lane], lr1 = lnr[lane + 64];
    float lk0 = lnk[lane], lk1 = lnk[lane + 64];

    for (int hb = hg * 4; hb < hg * 4 + 4; hb++) {
        int h = hb * 4 + w;
        int kv = h >> 2;
        float rk0 = rkg[h * 128 + lane], rk1 = rkg[h * 128 + 64 + lane];

        auto STEPQ = [&](int t, float cc, float ss,
                         float& Rr0, float& Rr1, float& Kf0, float& Kf1,
                         float& Aa0, float& Aa1, float& Bb0, float& Bb1,
                         float& Dd0, float& Dd1, float& Vv0, float& Vv1,
                         float& Gg0, float& Gg1) {
            size_t tS = (size_t)t * SR_;
            float r0 = COMB[tS + h * 128 + lane];
            float r1 = COMB[tS + h * 128 + 64 + lane];
            float sm = reduce64(r0 * r0 + r1 * r1);
            float sc = rsqrtf(sm * (1.f / 128.f) + 1e-6f);
            float rn0 = lr0 * r0 * sc, rn1 = lr1 * r1 * sc;
            Rr0 = rn0 * cc - rn1 * ss; Rr1 = rn1 * cc + rn0 * ss;
            float k0 = COMB[tS + 4096 + kv * 128 + lane];
            float k1 = COMB[tS + 4096 + kv * 128 + 64 + lane];
            float ks = reduce64(k0 * k0 + k1 * k1);
            float ksc = rsqrtf(ks * (1.f / 128.f) + 1e-6f);
            float kn0 = lk0 * k0 * ksc, kn1 = lk1 * k1 * ksc;
            float kr0 = kn0 * cc - kn1 * ss, kr1 = kn1 * cc + kn0 * ss;
            float nr = reduce64(kr0 * kr0 + kr1 * kr1);
            float inv = 1.f / fmaxf(sqrtf(nr), 1e-12f);
            float kk0 = kr0 * inv, kk1 = kr1 * inv;
            int ch0 = h * 128 + lane, ch1 = ch0 + 64;
            size_t tb = (size_t)t * HN_;
            float wv0 = -splus(-wpre[tb + ch0]) - 0.5f;
            float wv1 = -splus(-wpre[tb + ch1]) - 0.5f;
            Dd0 = expf(-expf(wv0)); Dd1 = expf(-expf(wv1));
            float av0 = sigm(apre[tb + ch0]);
            float av1 = sigm(apre[tb + ch1]);
            float vg0 = sigm(vgpre[tb + ch0]);
            float vg1 = sigm(vgpre[tb + ch1]);
            float vr0 = COMB[tS + 5120 + kv * 128 + lane];
            float vr1 = COMB[tS + 5120 + kv * 128 + 64 + lane];
            Vv0 = vr0 + (vfirst[tb + ch0] - vr0) * vg0;
            Vv1 = vr1 + (vfirst[tb + ch1] - vr1) * vg1;
            Kf0 = kr0 * (1.f - wv0 + av0); Kf1 = kr1 * (1.f - wv1 + av1);
            Aa0 = -kk0; Aa1 = -kk1;
            Bb0 = kk0 * av0; Bb1 = kk1 * av1;
            Gg0 = garr[tb + ch0]; Gg1 = garr[tb + ch1];
        };

        float r00, r01, k00, k01, a00, a01, b00, b01, d00, d01, v00, v01, g00, g01;
        float r10, r11, k10, k11, a10, a11, b10, b11, d10, d11, v10, v11, g10, g11;
        STEPQ(t0, cA, sA, r00, r01, k00, k01, a00, a01, b00, b01, d00, d01, v00, v01, g00, g01);
        STEPQ(t1, cB, sB, r10, r11, k10, k11, a10, a11, b10, b11, d10, d11, v10, v11, g10, g11);

        float* rf = (float*)(SFB + ((size_t)h * 128 + tp) * 3072);
        rf[0    + lane] = a00;        rf[0    + 64 + lane] = a01;         // A0
        rf[128  + lane] = d00 * a10;  rf[128  + 64 + lane] = d01 * a11;   // WA
        rf[256  + lane] = d00 * r00;  rf[256  + 64 + lane] = d01 * r01;   // WR
        rf[384  + lane] = r10;        rf[384  + 64 + lane] = r11;         // R1
        rf[512  + lane] = d00 * d10;  rf[512  + 64 + lane] = d01 * d11;   // W2
        rf[640  + lane] = b00 * d10;  rf[640  + 64 + lane] = b01 * d11;   // BW
        rf[768  + lane] = k00 * d10;  rf[768  + 64 + lane] = k01 * d11;   // KW
        rf[896  + lane] = b10;        rf[896  + 64 + lane] = b11;         // B1
        rf[1024 + lane] = k10;        rf[1024 + 64 + lane] = k11;         // K1
        ushort* us = (ushort*)rf;
        us[2304 + lane] = (ushort)f2bf(v00); us[2304 + 64 + lane] = (ushort)f2bf(v01);
        us[2432 + lane] = (ushort)f2bf(v10); us[2432 + 64 + lane] = (ushort)f2bf(v11);
        us[2560 + lane] = (ushort)f2bf(g00); us[2560 + 64 + lane] = (ushort)f2bf(g01);
        us[2688 + lane] = (ushort)f2bf(g10); us[2688 + 64 + lane] = (ushort)f2bf(g11);

        float C1  = reduce64(b00 * a10 + b01 * a11);
        float C2  = reduce64(k00 * a10 + k01 * a11);
        float C3  = reduce64(b00 * r00 + b01 * r01);
        float C4  = reduce64(k00 * r00 + k01 * r01);
        float BD0 = reduce64(r00 * k00 * rk0 + r01 * k01 * rk1);
        float BD1 = reduce64(r10 * k10 * rk0 + r11 * k11 * rk1);
        if (lane == 0) {
            rf[1408] = C1; rf[1409] = C2; rf[1410] = C3;
            rf[1411] = C4; rf[1412] = BD0; rf[1413] = BD1;
        }
    }
}

// ---------------- scan v3: barrier-free register-direct, 4 indep waves/block -----
// grid (32 heads, 32 splits) = 1024 blocks x 256 thr. NO LDS, NO barriers.
// Each wave double-buffers two pair-records in registers (static indexing);
// compiler-scheduled waitcnt. One STEP (~interleave of 4 reduce64) of latency
// cover per buffer; SF stream is L2-resident (h%8 XCD affinity).
struct Rec {
    float2 A0, WA, WR, R1, W2, BW, KW, B1, K1;
    float vi0, vi1, gi0, gi1;
    float2 c12, c34, bdp;
};
__global__ __launch_bounds__(256) void scan_k(
    const float* __restrict__ state_in,
    const ushort* __restrict__ SFB,
    ushort* __restrict__ yb, float* __restrict__ Sout) {
    const int h = blockIdx.x, sp = blockIdx.y;
    const int tid = threadIdx.x;
    const int wv = tid >> 6, ln = tid & 63;
    const int i = sp * 4 + wv;           // row this wave owns
    const int j0 = ln * 2;

    float S0, S1;
    {
        float2 s2 = *(const float2*)(state_in + ((size_t)h * 128 + i) * 128 + j0);
        S0 = s2.x; S1 = s2.y;
    }

    const ushort* hbase = SFB + (size_t)h * 128 * 3072;

    auto LOADR = [&](Rec& R, int tp) {
        const float* Lf = (const float*)(hbase + (size_t)tp * 3072);
        const ushort* Lu = (const ushort*)Lf;
        R.A0 = *(const float2*)(Lf + 0    + j0);
        R.WA = *(const float2*)(Lf + 128  + j0);
        R.WR = *(const float2*)(Lf + 256  + j0);
        R.R1 = *(const float2*)(Lf + 384  + j0);
        R.W2 = *(const float2*)(Lf + 512  + j0);
        R.BW = *(const float2*)(Lf + 640  + j0);
        R.KW = *(const float2*)(Lf + 768  + j0);
        R.B1 = *(const float2*)(Lf + 896  + j0);
        R.K1 = *(const float2*)(Lf + 1024 + j0);
        R.vi0 = bf1(Lu[2304 + i]);
        R.vi1 = bf1(Lu[2432 + i]);
        R.gi0 = bf1(Lu[2560 + i]);
        R.gi1 = bf1(Lu[2688 + i]);
        R.c12 = *(const float2*)(Lf + 1408);
        R.c34 = *(const float2*)(Lf + 1410);
        R.bdp = *(const float2*)(Lf + 1412);
    };

    float pend_y0 = 0.f, pend_y1 = 0.f;
    float r1c0 = 0.f, r1c1 = 0.f, bd1c = 0.f, vi1c = 0.f, gi1c = 0.f;

    auto STEP = [&](const Rec& R, int I) {
        // store y for prior pairs (no ordering constraints -- compiler waitcnt)
        if (ln == 0 && I >= 1)
            yb[(size_t)(2 * I - 2) * HN_ + h * 128 + i] = (ushort)f2bf(pend_y0);
        if (ln == 0 && I >= 2)
            yb[(size_t)(2 * I - 3) * HN_ + h * 128 + i] = (ushort)f2bf(pend_y1);

        float up = fmaf(S0, R.A0.x, S1 * R.A0.y);
        float pp = fmaf(S0, R.WA.x, S1 * R.WA.y);
        float yp = fmaf(S0, R.WR.x, S1 * R.WR.y);
        float op = fmaf(S0, r1c0, S1 * r1c1);
        float u_   = reduce64(up);
        float p_   = reduce64(pp);
        float yb0  = reduce64(yp);
        float od1  = reduce64(op);

        pend_y1 = fmaf(od1, 0.08838834764831845f, bd1c * vi1c) * gi1c;

        float sa0 = u_;
        float sa1 = fmaf(sa0, R.c12.x, fmaf(R.vi0, R.c12.y, p_));
        float od0 = fmaf(sa0, R.c34.x, fmaf(R.vi0, R.c34.y, yb0));
        pend_y0 = fmaf(od0, 0.08838834764831845f, R.bdp.x * R.vi0) * R.gi0;

        S0 = fmaf(sa0, R.BW.x, S0 * R.W2.x);
        S0 = fmaf(R.vi0, R.KW.x, S0);
        S0 = fmaf(sa1, R.B1.x, S0);
        S0 = fmaf(R.vi1, R.K1.x, S0);
        S1 = fmaf(sa0, R.BW.y, S1 * R.W2.y);
        S1 = fmaf(R.vi0, R.KW.y, S1);
        S1 = fmaf(sa1, R.B1.y, S1);
        S1 = fmaf(R.vi1, R.K1.y, S1);

        r1c0 = R.R1.x; r1c1 = R.R1.y;
        bd1c = R.bdp.y; vi1c = R.vi1; gi1c = R.gi1;
    };

    Rec RA, RB;
    LOADR(RA, 0);
    LOADR(RB, 1);
    for (int I = 0; I < 128; I += 2) {
        STEP(RA, I);
        if (I + 2 < 128) LOADR(RA, I + 2);
        STEP(RB, I + 1);
        if (I + 3 < 128) LOADR(RB, I + 3);
    }

    // tail: y0(127)->t=254, y1(126)->t=253 pending; finalize y1(127)->t=255
    {
        float op = fmaf(S0, r1c0, S1 * r1c1);
        float od1 = reduce64(op);
        float cp1 = fmaf(od1, 0.08838834764831845f, bd1c * vi1c) * gi1c;
        if (ln == 0) {
            yb[(size_t)255 * HN_ + h * 128 + i] = (ushort)f2bf(cp1);
            yb[(size_t)254 * HN_ + h * 128 + i] = (ushort)f2bf(pend_y0);
            yb[(size_t)253 * HN_ + h * 128 + i] = (ushort)f2bf(pend_y1);
        }
    }

    float* pS = Sout + ((size_t)h * 128 + i) * 128 + j0;
    *(float2*)pS = make_float2(S0, S1);
}

// =====================================================================================
extern "C" void kernel_launch(void* const* d_in, const int* in_sizes, int n_in,
                              void* d_out, int out_size, void* d_ws, size_t ws_size,
                              hipStream_t stream) {
    const float* x_in   = (const float*)d_in[0];
    const float* vfirst = (const float*)d_in[1];
    const float* state  = (const float*)d_in[2];
    const int*   cpos   = (const int*)d_in[3];
    const float* w0 = (const float*)d_in[4];
    const float* w1 = (const float*)d_in[5];
    const float* w2 = (const float*)d_in[6];
    const float* a0 = (const float*)d_in[7];
    const float* a1 = (const float*)d_in[8];
    const float* a2 = (const float*)d_in[9];
    const float* v0 = (const float*)d_in[10];
    const float* v1 = (const float*)d_in[11];
    const float* v2 = (const float*)d_in[12];
    const float* g1 = (const float*)d_in[13];
    const float* g2 = (const float*)d_in[14];
    const float* r_k = (const float*)d_in[15];
    const float* R_ = (const float*)d_in[16];
    const float* K_ = (const float*)d_in[17];
    const float* V_ = (const float*)d_in[18];
    const float* O_ = (const float*)d_in[19];
    const float* Rb = (const float*)d_in[20];
    const float* Kb = (const float*)d_in[21];
    const float* Vb = (const float*)d_in[22];
    const float* ln_r = (const float*)d_in[23];
    const float* ln_k = (const float*)d_in[24];
    const float* ln1 = (const float*)d_in[25];
    const float* ln2 = (const float*)d_in[26];

    float* ws = (float*)d_ws;
    constexpr size_t OFF_XB   = 0;          // bf16 [256][4096]
    constexpr size_t OFF_COMB = 524288;     // f32 [256][6464]
    constexpr size_t OFF_WT   = 2179072;    // f32 [320][4096]
    constexpr size_t OFF_TCB  = 3489792;    // bf16 [256][320] = 40960 f32
    constexpr size_t OFF_WPRE = 3530752;
    constexpr size_t OFF_APRE = 4579328;
    constexpr size_t OFF_VGPRE= 5627904;
    constexpr size_t OFF_G    = 6676480;
    constexpr size_t OFF_SF   = 7757824;    // pair stream: 32*128*6144B
    constexpr size_t OFF_YB   = OFF_XB;     // alias (XB dead before scan)

    ushort* XB  = (ushort*)(ws + OFF_XB);
    float* COMB = ws + OFF_COMB;
    float* WT   = ws + OFF_WT;
    ushort* TCB = (ushort*)(ws + OFF_TCB);
    float* WPRE = ws + OFF_WPRE;
    float* APRE = ws + OFF_APRE;
    float* VGPRE= ws + OFF_VGPRE;
    float* GARR = ws + OFF_G;
    ushort* SFB = (ushort*)(ws + OFF_SF);
    ushort* YB  = (ushort*)(ws + OFF_YB);

    float* out = (float*)d_out;
    float* out0  = out;
    float* xlast = out + 1048576;
    float* Sfin  = out + 1052672;
    float* vfout = out + 1576960;
    float* xres  = out + 2625536;

    hipMemcpyAsync(vfout, vfirst, (size_t)1048576 * 4, hipMemcpyDeviceToDevice, stream);
    hipMemcpyAsync(xres, x_in, (size_t)1048576 * 4, hipMemcpyDeviceToDevice, stream);

    rmsnorm_k<<<T_, 256, 0, stream>>>(x_in, ln1, nullptr, XB, xlast);

    wcat2_k<<<dim3(64, 5), 256, 0, stream>>>(w1, a1, v1, g1, WT);
    hipMemsetAsync(WT + (size_t)288 * 4096, 0, (size_t)32 * 4096 * 4, stream);
    init_comb_k<<<T_, 256, 0, stream>>>(Rb, Kb, Vb, COMB);

    gemm_rkvt<<<dim3(202, 4), 512, 0, stream>>>(XB, R_, K_, V_, WT, COMB);

    act_k<<<288, 256, 0, stream>>>(COMB, TCB);

    gemm_s2<<<dim3(128, 4), 512, 0, stream>>>(TCB, w2, a2, v2, g2, w0, a0, v0,
                                              WPRE, APRE, VGPRE, GARR);

    prep_k<<<dim3(128, 2), 256, 0, stream>>>(COMB, WPRE, APRE, VGPRE, vfirst, GARR,
                                             r_k, cpos, ln_r, ln_k, SFB);

    scan_k<<<dim3(32, 32), 256, 0, stream>>>(state, SFB, YB, Sfin);

    gemm_o<<<dim3(128, 4), 512, 0, stream>>>(YB, O_, xres);

    rmsnorm_k<<<T_, 256, 0, stream>>>(xres, ln2, out0, nullptr, nullptr);
}

// Round 19
// 270.205 us; speedup vs baseline: 1.2866x; 1.2866x over previous
//
#include <hip/hip_runtime.h>
#include <cstdint>
#include <cstddef>

#define T_ 256
#define HN_ 4096
#define H_ 32
#define N_ 128
#define SR_ 6464   // COMB row stride (4096 R + 1024 K + 1024 V + 320 T)

typedef __attribute__((ext_vector_type(8))) short short8;
typedef __attribute__((ext_vector_type(4))) float f32x4;

__device__ __forceinline__ short f2bf(float f) {
    uint32_t u = __builtin_bit_cast(uint32_t, f);
    u = (u + 0x7fffu + ((u >> 16) & 1u)) >> 16;   // RNE f32->bf16
    return (short)u;
}
__device__ __forceinline__ short f2bfc(float f) {  // cheap round-half-up
    return (short)((__builtin_bit_cast(uint32_t, f) + 0x8000u) >> 16);
}
__device__ __forceinline__ short8 cvt8r(float4 lo, float4 hi) {
    short8 v;
    v[0] = f2bfc(lo.x); v[1] = f2bfc(lo.y); v[2] = f2bfc(lo.z); v[3] = f2bfc(lo.w);
    v[4] = f2bfc(hi.x); v[5] = f2bfc(hi.y); v[6] = f2bfc(hi.z); v[7] = f2bfc(hi.w);
    return v;
}
__device__ __forceinline__ f32x4 mfma16(short8 a, short8 b, f32x4 c) {
    return __builtin_amdgcn_mfma_f32_16x16x32_bf16(a, b, c, 0, 0, 0);
}
__device__ __forceinline__ float sigm(float x) { return 1.f / (1.f + expf(-x)); }
__device__ __forceinline__ float splus(float x) { return (x > 20.f) ? x : log1pf(expf(x)); }

__device__ __forceinline__ float bf1(ushort u) {
    return __builtin_bit_cast(float, (uint32_t)u << 16);
}
__device__ __forceinline__ void gload_lds16(const void* g, void* l) {
    __builtin_amdgcn_global_load_lds(
        (const __attribute__((address_space(1))) void*)g,
        (__attribute__((address_space(3))) void*)l, 16, 0, 0);
}

// ---- DPP cross-lane add (VALU pipe) --------------------------------------------
template <int CTRL>
__device__ __forceinline__ float dpp_add(float v) {
    int p = __builtin_amdgcn_mov_dpp(__builtin_bit_cast(int, v), CTRL, 0xF, 0xF, true);
    return v + __builtin_bit_cast(float, p);
}
// Full 64-lane reduce -> uniform scalar (DS-free; verified R12)
__device__ __forceinline__ float reduce64(float v) {
    v = dpp_add<0xB1>(v);     // quad_perm [1,0,3,2]  (xor 1)
    v = dpp_add<0x4E>(v);     // quad_perm [2,3,0,1]  (xor 2)
    v = dpp_add<0x124>(v);    // row_ror:4
    v = dpp_add<0x128>(v);    // row_ror:8
    v = dpp_add<0x142>(v);    // row_bcast:15
    v = dpp_add<0x143>(v);    // row_bcast:31
    int r = __builtin_amdgcn_readlane(__builtin_bit_cast(int, v), 63);
    return __builtin_bit_cast(float, r);
}

// ---- GEMM core v2: B dequantized ONCE per stage into bf16 LDS tile (R16) --------
__device__ __forceinline__ void gemm_core(
    const ushort* __restrict__ A, const float* __restrict__ Brow,
    int kbeg, ushort* LH, f32x4 acc[2][2]) {
    const int tid = threadIdx.x, wid = tid >> 6, l = tid & 63;
    const int ar = l & 15, ak = (l >> 4) * 8;
    const int mBase = wid * 32;

    const int brw = tid >> 4, bc8 = tid & 15;
    const float* bsrc = Brow + (size_t)brw * 4096 + kbeg + bc8 * 8;
    const int hoff = brw * 128 + ((bc8 ^ (brw & 7)) * 8);

    const ushort* pa0 = A + (size_t)(mBase + ar) * 4096 + kbeg + ak;
    const ushort* pa1 = pa0 + (size_t)16 * 4096;

    const int akc = ak >> 3;
    const int sx0 = ar & 7;
    const int rb0 = ar * 128, rb1 = (16 + ar) * 128;

    short8 Ae[8], Ao[8];
    float4 B0a, B0b, B1a, B1b;

#define LB0(s) { B0a = *(const float4*)(bsrc + (size_t)(s) * 128); \
                 B0b = *(const float4*)(bsrc + (size_t)(s) * 128 + 4); }
#define LB1(s) { B1a = *(const float4*)(bsrc + (size_t)(s) * 128); \
                 B1b = *(const float4*)(bsrc + (size_t)(s) * 128 + 4); }

#define LA(B_, s) { \
    B_[0] = *(const short8*)(pa0 + (size_t)(s) * 128);      \
    B_[1] = *(const short8*)(pa1 + (size_t)(s) * 128);      \
    B_[2] = *(const short8*)(pa0 + (size_t)(s) * 128 + 32); \
    B_[3] = *(const short8*)(pa1 + (size_t)(s) * 128 + 32); \
    B_[4] = *(const short8*)(pa0 + (size_t)(s) * 128 + 64); \
    B_[5] = *(const short8*)(pa1 + (size_t)(s) * 128 + 64); \
    B_[6] = *(const short8*)(pa0 + (size_t)(s) * 128 + 96); \
    B_[7] = *(const short8*)(pa1 + (size_t)(s) * 128 + 96); }

#define CKK(kk, B_, Hb_) { \
    const int sl = ((kk) * 4 + akc) ^ sx0; \
    short8 b0 = *(const short8*)((Hb_) + rb0 + sl * 8); \
    short8 b1 = *(const short8*)((Hb_) + rb1 + sl * 8); \
    acc[0][0] = mfma16(B_[2 * (kk)], b0, acc[0][0]); \
    acc[0][1] = mfma16(B_[2 * (kk)], b1, acc[0][1]); \
    acc[1][0] = mfma16(B_[2 * (kk) + 1], b0, acc[1][0]); \
    acc[1][1] = mfma16(B_[2 * (kk) + 1], b1, acc[1][1]); }

#define COMPUTE(Hb_, B_) { CKK(0, B_, Hb_) CKK(1, B_, Hb_) CKK(2, B_, Hb_) CKK(3, B_, Hb_) }

    LB0(0)
    LA(Ae, 0)
    LB1(1)

    for (int su = 0; su < 4; su++) {
        const int s0 = su * 2, s1 = su * 2 + 1;

        *(short8*)(LH + hoff) = cvt8r(B0a, B0b);
        LB0((s0 + 2 < 8) ? s0 + 2 : 7)
        LA(Ao, s0 + 1)
        asm volatile("s_waitcnt lgkmcnt(0)" ::: "memory");
        __builtin_amdgcn_s_barrier();
        __builtin_amdgcn_sched_barrier(0);
        COMPUTE(LH, Ae)

        *(short8*)(LH + 4096 + hoff) = cvt8r(B1a, B1b);
        LB1((s1 + 2 < 8) ? s1 + 2 : 7)
        LA(Ae, (s1 + 1 < 8) ? s1 + 1 : 7)
        asm volatile("s_waitcnt lgkmcnt(0)" ::: "memory");
        __builtin_amdgcn_s_barrier();
        __builtin_amdgcn_sched_barrier(0);
        COMPUTE(LH + 4096, Ao)
    }
#undef LB0
#undef LB1
#undef LA
#undef CKK
#undef COMPUTE
}

// ---------------- RMSNorm over 4096; f32/bf16 outs, lastrow, raw copy ------------
__global__ __launch_bounds__(256) void rmsnorm_k(const float* __restrict__ in,
                                                 const float* __restrict__ w,
                                                 float* __restrict__ outF,
                                                 ushort* __restrict__ outB,
                                                 float* __restrict__ lastrow,
                                                 float* __restrict__ rawcopy) {
    int t = blockIdx.x, tid = threadIdx.x;
    const float4* in4 = (const float4*)(in + (size_t)t * HN_);
    const float4* w4 = (const float4*)w;
    float4 v[4]; float ss = 0.f;
#pragma unroll
    for (int q = 0; q < 4; q++) {
        v[q] = in4[q * 256 + tid];
        ss += v[q].x * v[q].x + v[q].y * v[q].y + v[q].z * v[q].z + v[q].w * v[q].w;
    }
#pragma unroll
    for (int o = 32; o; o >>= 1) ss += __shfl_down(ss, o);
    __shared__ float red[4];
    if ((tid & 63) == 0) red[tid >> 6] = ss;
    __syncthreads();
    float tot = red[0] + red[1] + red[2] + red[3];
    float sc = rsqrtf(tot * (1.f / HN_) + 1e-6f);
#pragma unroll
    for (int q = 0; q < 4; q++) {
        float4 wv = w4[q * 256 + tid];
        float4 r;
        r.x = wv.x * v[q].x * sc; r.y = wv.y * v[q].y * sc;
        r.z = wv.z * v[q].z * sc; r.w = wv.w * v[q].w * sc;
        int idx = q * 256 + tid;
        if (outF) ((float4*)(outF + (size_t)t * HN_))[idx] = r;
        if (outB) {
            ushort4 b;
            b.x = (ushort)f2bf(r.x); b.y = (ushort)f2bf(r.y);
            b.z = (ushort)f2bf(r.z); b.w = (ushort)f2bf(r.w);
            ((ushort4*)(outB + (size_t)t * HN_))[idx] = b;
        }
        if (rawcopy) ((float4*)(rawcopy + (size_t)t * HN_))[idx] = v[q];
        if (lastrow && t == T_ - 1) ((float4*)lastrow)[idx] = r;
    }
}

// ---------------- fused R/K/V/LoRA1 split-K GEMM, atomic epilogue into COMB ------
__global__ __launch_bounds__(512, 2) void gemm_rkvt(
    const ushort* __restrict__ A,
    const float* __restrict__ Rw, const float* __restrict__ Kw,
    const float* __restrict__ Vw, const float* __restrict__ WT,
    float* __restrict__ COMB) {
    __shared__ __align__(16) ushort LH[8192];
    const int tid = threadIdx.x, wid = tid >> 6, l = tid & 63;
    const int mBase = wid * 32;
    const int nB = blockIdx.x * 32;
    const int kbeg = blockIdx.y * 1024;

    const float* Bp; int brow;
    if (nB < 4096)      { Bp = Rw; brow = nB; }
    else if (nB < 5120) { Bp = Kw; brow = nB - 4096; }
    else if (nB < 6144) { Bp = Vw; brow = nB - 5120; }
    else                { Bp = WT; brow = nB - 6144; }

    f32x4 acc[2][2];
#pragma unroll
    for (int i = 0; i < 2; i++)
#pragma unroll
        for (int j = 0; j < 2; j++) acc[i][j] = f32x4{0.f, 0.f, 0.f, 0.f};

    gemm_core(A, Bp + (size_t)brow * 4096, kbeg, LH, acc);

    const int rl = (l >> 4) * 4, cl = l & 15;
#pragma unroll
    for (int mf = 0; mf < 2; mf++)
#pragma unroll
        for (int nf = 0; nf < 2; nf++)
#pragma unroll
            for (int e = 0; e < 4; e++)
                unsafeAtomicAdd(&COMB[(size_t)(mBase + mf * 16 + rl + e) * SR_ + nB + nf * 16 + cl],
                                acc[mf][nf][e]);
}

// ---------------- O GEMM: xres += YB @ O^T (atomic, split-K) ---------------------
__global__ __launch_bounds__(512, 2) void gemm_o(
    const ushort* __restrict__ A,
    const float* __restrict__ B,
    float* __restrict__ C) {
    __shared__ __align__(16) ushort LH[8192];
    const int tid = threadIdx.x, wid = tid >> 6, l = tid & 63;
    const int mBase = wid * 32;
    const int nB = blockIdx.x * 32;
    const int kbeg = blockIdx.y * 1024;

    f32x4 acc[2][2];
#pragma unroll
    for (int i = 0; i < 2; i++)
#pragma unroll
        for (int j = 0; j < 2; j++) acc[i][j] = f32x4{0.f, 0.f, 0.f, 0.f};

    gemm_core(A, B + (size_t)nB * 4096, kbeg, LH, acc);

    const int rl = (l >> 4) * 4, cl = l & 15;
#pragma unroll
    for (int mf = 0; mf < 2; mf++)
#pragma unroll
        for (int nf = 0; nf < 2; nf++)
#pragma unroll
            for (int e = 0; e < 4; e++)
                unsafeAtomicAdd(&C[(size_t)(mBase + mf * 16 + rl + e) * 4096 + nB + nf * 16 + cl],
                                acc[mf][nf][e]);
}

// ---------------- fused stage-2 LoRA GEMMs (4 segments, bf16 outputs) ------------
__global__ __launch_bounds__(512) void gemm_s2(
    const ushort* __restrict__ TCB,
    const float* __restrict__ w2, const float* __restrict__ a2,
    const float* __restrict__ v2, const float* __restrict__ g2,
    const float* __restrict__ w0, const float* __restrict__ a0,
    const float* __restrict__ v0,
    ushort* __restrict__ WPRE, ushort* __restrict__ APRE,
    ushort* __restrict__ VGPRE, ushort* __restrict__ GARR) {
    const int z = blockIdx.y;
    int Aoff, K; const float* B; const float* bias; ushort* out;
    if (z == 0)      { Aoff = 0;   K = 64;  B = w2; bias = w0;      out = WPRE; }
    else if (z == 1) { Aoff = 64;  K = 64;  B = a2; bias = a0;      out = APRE; }
    else if (z == 2) { Aoff = 128; K = 32;  B = v2; bias = v0;      out = VGPRE; }
    else             { Aoff = 160; K = 128; B = g2; bias = nullptr; out = GARR; }

    const int tid = threadIdx.x, wid = tid >> 6, l = tid & 63;
    const int ar = l & 15, ak = (l >> 4) * 8;
    const int mBase = wid * 32;
    const int nB = blockIdx.x * 32;

    f32x4 acc[2][2];
#pragma unroll
    for (int i = 0; i < 2; i++)
#pragma unroll
        for (int j = 0; j < 2; j++) acc[i][j] = f32x4{0.f, 0.f, 0.f, 0.f};

    for (int k0 = 0; k0 < K; k0 += 32) {
        const ushort* pA = TCB + (size_t)(mBase + ar) * 320 + Aoff + k0 + ak;
        short8 av0 = *(const short8*)pA;
        short8 av1 = *(const short8*)(pA + (size_t)16 * 320);
        short8 bv0, bv1;
#pragma unroll
        for (int e = 0; e < 8; e++) {
            bv0[e] = f2bfc(B[(size_t)(k0 + ak + e) * 4096 + nB + ar]);
            bv1[e] = f2bfc(B[(size_t)(k0 + ak + e) * 4096 + nB + 16 + ar]);
        }
        acc[0][0] = mfma16(av0, bv0, acc[0][0]);
        acc[0][1] = mfma16(av0, bv1, acc[0][1]);
        acc[1][0] = mfma16(av1, bv0, acc[1][0]);
        acc[1][1] = mfma16(av1, bv1, acc[1][1]);
    }
    const int rl = (l >> 4) * 4, cl = l & 15;
#pragma unroll
    for (int mf = 0; mf < 2; mf++)
#pragma unroll
        for (int nf = 0; nf < 2; nf++) {
            int col = nB + nf * 16 + cl;
            float bv = bias ? bias[col] : 0.f;
#pragma unroll
            for (int e = 0; e < 4; e++)
                out[(size_t)(mBase + mf * 16 + rl + e) * 4096 + col] =
                    (ushort)f2bf(acc[mf][nf][e] + bv);
        }
}

// ---------------- LoRA-A concat-transpose via LDS tiles -> WT[320][4096] ---------
__global__ __launch_bounds__(256) void wcat2_k(const float* __restrict__ w1p,
                                               const float* __restrict__ a1p,
                                               const float* __restrict__ v1p,
                                               const float* __restrict__ g1p,
                                               float* __restrict__ WT) {
    const int kb = blockIdx.x * 64, tile = blockIdx.y;
    const float* src; int ldw, jo, nb, W;
    if (tile == 0)      { src = w1p; ldw = 64;  jo = 0;  nb = 0;   W = 64; }
    else if (tile == 1) { src = a1p; ldw = 64;  jo = 0;  nb = 64;  W = 64; }
    else if (tile == 2) { src = v1p; ldw = 32;  jo = 0;  nb = 128; W = 32; }
    else if (tile == 3) { src = g1p; ldw = 128; jo = 0;  nb = 160; W = 64; }
    else                { src = g1p; ldw = 128; jo = 64; nb = 224; W = 64; }
    __shared__ float lds[64][65];
    const int ti = threadIdx.x & 63, wi = threadIdx.x >> 6;
    if (ti < W)
        for (int i = wi; i < 64; i += 4)
            lds[i][ti] = src[(size_t)(kb + i) * ldw + jo + ti];
    __syncthreads();
    for (int i2 = wi; i2 < W; i2 += 4)
        WT[(size_t)(nb + i2) * 4096 + kb + ti] = lds[ti][i2];
}

// ---------------- init COMB rows with biases -------------------------------------
__global__ __launch_bounds__(256) void init_comb_k(const float* __restrict__ Rb,
                                                   const float* __restrict__ Kb,
                                                   const float* __restrict__ Vb,
                                                   float* __restrict__ COMB) {
    int t = blockIdx.x;
    for (int c = threadIdx.x; c < SR_; c += 256) {
        float b = (c < 4096) ? Rb[c] : (c < 5120) ? Kb[c - 4096]
                : (c < 6144) ? Vb[c - 5120] : 0.f;
        COMB[(size_t)t * SR_ + c] = b;
    }
}

// ---------------- activations on TCAT cols of COMB -> TCB bf16 [256][320] --------
__global__ __launch_bounds__(256) void act_k(const float* __restrict__ COMB,
                                             ushort* __restrict__ TCB) {
    int idx = blockIdx.x * 256 + threadIdx.x;
    if (idx >= 256 * 288) return;
    int t = idx / 288, c = idx % 288;
    float v = COMB[(size_t)t * SR_ + 6144 + c];
    if (c < 64) v = tanhf(v);
    else if (c >= 160) v = sigm(v);
    TCB[t * 320 + c] = (ushort)f2bf(v);
}

// ---------------- prep: pairwise (L=2) scan stream, rope fused (bf16 gate ins) ---
__global__ __launch_bounds__(256) void prep_k(
    const float* __restrict__ COMB, const ushort* __restrict__ wpre,
    const ushort* __restrict__ apre, const ushort* __restrict__ vgpre,
    const float* __restrict__ vfirst, const ushort* __restrict__ garr,
    const float* __restrict__ rkg, const int* __restrict__ cpos,
    const float* __restrict__ lnr, const float* __restrict__ lnk,
    ushort* __restrict__ SFB) {
    const int tp = blockIdx.x, hg = blockIdx.y;
    const int tid = threadIdx.x;
    const int w = tid >> 6, lane = tid & 63;
    const int t0 = tp * 2, t1 = t0 + 1;

    float e = (float)lane * (1.f / 64.f);
    float inv_s = exp2f(-13.287712379549449f * e);
    float inv_l = exp2f(-13.287712379549449f - 3.321928094887362f * e);
    float base = (float)cpos[0];
    float pos0 = base + (float)t0, pos1 = base + (float)t1;
    float mix0 = fminf(fmaxf(pos0 * (1.f / 4096.f), 0.f), 1.f);
    float mix1 = fminf(fmaxf(pos1 * (1.f / 4096.f), 0.f), 1.f);
    float fr0 = pos0 * ((1.f - mix0) * inv_s + mix0 * inv_l);
    float fr1 = pos1 * ((1.f - mix1) * inv_s + mix1 * inv_l);
    float cA = cosf(fr0), sA = sinf(fr0);
    float cB = cosf(fr1), sB = sinf(fr1);

    float lr0 = lnr[lane], lr1 = lnr[lane + 64];
    float lk0 = lnk[lane], lk1 = lnk[lane + 64];

    for (int hb = hg * 4; hb < hg * 4 + 4; hb++) {
        int h = hb * 4 + w;
        int kv = h >> 2;
        float rk0 = rkg[h * 128 + lane], rk1 = rkg[h * 128 + 64 + lane];

        auto STEPQ = [&](int t, float cc, float ss,
                         float& Rr0, float& Rr1, float& Kf0, float& Kf1,
                         float& Aa0, float& Aa1, float& Bb0, float& Bb1,
                         float& Dd0, float& Dd1, float& Vv0, float& Vv1,
                         float& Gg0, float& Gg1) {
            size_t tS = (size_t)t * SR_;
            float r0 = COMB[tS + h * 128 + lane];
            float r1 = COMB[tS + h * 128 + 64 + lane];
            float sm = reduce64(r0 * r0 + r1 * r1);
            float sc = rsqrtf(sm * (1.f / 128.f) + 1e-6f);
            float rn0 = lr0 * r0 * sc, rn1 = lr1 * r1 * sc;
            Rr0 = rn0 * cc - rn1 * ss; Rr1 = rn1 * cc + rn0 * ss;
            float k0 = COMB[tS + 4096 + kv * 128 + lane];
            float k1 = COMB[tS + 4096 + kv * 128 + 64 + lane];
            float ks = reduce64(k0 * k0 + k1 * k1);
            float ksc = rsqrtf(ks * (1.f / 128.f) + 1e-6f);
            float kn0 = lk0 * k0 * ksc, kn1 = lk1 * k1 * ksc;
            float kr0 = kn0 * cc - kn1 * ss, kr1 = kn1 * cc + kn0 * ss;
            float nr = reduce64(kr0 * kr0 + kr1 * kr1);
            float inv = 1.f / fmaxf(sqrtf(nr), 1e-12f);
            float kk0 = kr0 * inv, kk1 = kr1 * inv;
            int ch0 = h * 128 + lane, ch1 = ch0 + 64;
            size_t tb = (size_t)t * HN_;
            float wv0 = -splus(-bf1(wpre[tb + ch0])) - 0.5f;
            float wv1 = -splus(-bf1(wpre[tb + ch1])) - 0.5f;
            Dd0 = expf(-expf(wv0)); Dd1 = expf(-expf(wv1));
            float av0 = sigm(bf1(apre[tb + ch0]));
            float av1 = sigm(bf1(apre[tb + ch1]));
            float vg0 = sigm(bf1(vgpre[tb + ch0]));
            float vg1 = sigm(bf1(vgpre[tb + ch1]));
            float vr0 = COMB[tS + 5120 + kv * 128 + lane];
            float vr1 = COMB[tS + 5120 + kv * 128 + 64 + lane];
            Vv0 = vr0 + (vfirst[tb + ch0] - vr0) * vg0;
            Vv1 = vr1 + (vfirst[tb + ch1] - vr1) * vg1;
            Kf0 = kr0 * (1.f - wv0 + av0); Kf1 = kr1 * (1.f - wv1 + av1);
            Aa0 = -kk0; Aa1 = -kk1;
            Bb0 = kk0 * av0; Bb1 = kk1 * av1;
            Gg0 = bf1(garr[tb + ch0]); Gg1 = bf1(garr[tb + ch1]);
        };

        float r00, r01, k00, k01, a00, a01, b00, b01, d00, d01, v00, v01, g00, g01;
        float r10, r11, k10, k11, a10, a11, b10, b11, d10, d11, v10, v11, g10, g11;
        STEPQ(t0, cA, sA, r00, r01, k00, k01, a00, a01, b00, b01, d00, d01, v00, v01, g00, g01);
        STEPQ(t1, cB, sB, r10, r11, k10, k11, a10, a11, b10, b11, d10, d11, v10, v11, g10, g11);

        float* rf = (float*)(SFB + ((size_t)h * 128 + tp) * 3072);
        rf[0    + lane] = a00;        rf[0    + 64 + lane] = a01;         // A0
        rf[128  + lane] = d00 * a10;  rf[128  + 64 + lane] = d01 * a11;   // WA
        rf[256  + lane] = d00 * r00;  rf[256  + 64 + lane] = d01 * r01;   // WR
        rf[384  + lane] = r10;        rf[384  + 64 + lane] = r11;         // R1
        rf[512  + lane] = d00 * d10;  rf[512  + 64 + lane] = d01 * d11;   // W2
        rf[640  + lane] = b00 * d10;  rf[640  + 64 + lane] = b01 * d11;   // BW
        rf[768  + lane] = k00 * d10;  rf[768  + 64 + lane] = k01 * d11;   // KW
        rf[896  + lane] = b10;        rf[896  + 64 + lane] = b11;         // B1
        rf[1024 + lane] = k10;        rf[1024 + 64 + lane] = k11;         // K1
        ushort* us = (ushort*)rf;
        us[2304 + lane] = (ushort)f2bf(v00); us[2304 + 64 + lane] = (ushort)f2bf(v01);
        us[2432 + lane] = (ushort)f2bf(v10); us[2432 + 64 + lane] = (ushort)f2bf(v11);
        us[2560 + lane] = (ushort)f2bf(g00); us[2560 + 64 + lane] = (ushort)f2bf(g01);
        us[2688 + lane] = (ushort)f2bf(g10); us[2688 + 64 + lane] = (ushort)f2bf(g11);

        float C1  = reduce64(b00 * a10 + b01 * a11);
        float C2  = reduce64(k00 * a10 + k01 * a11);
        float C3  = reduce64(b00 * r00 + b01 * r01);
        float C4  = reduce64(k00 * r00 + k01 * r01);
        float BD0 = reduce64(r00 * k00 * rk0 + r01 * k01 * rk1);
        float BD1 = reduce64(r10 * k10 * rk0 + r11 * k11 * rk1);
        if (lane == 0) {
            rf[1408] = C1; rf[1409] = C2; rf[1410] = C3;
            rf[1411] = C4; rf[1412] = BD0; rf[1413] = BD1;
        }
    }
}

// ---------------- scan: L=2 pairs, 4-wave blocks (proven R15/R16 shell) ----------
#define SDP_ 5     // prefetch depth (pairs in flight)
#define SNBP_ 6    // ring buffers
__global__ __launch_bounds__(256) void scan_k(
    const float* __restrict__ state_in,
    const ushort* __restrict__ SFB,
    ushort* __restrict__ yb, float* __restrict__ Sout,
    ushort* __restrict__ dummy) {
    const int h = blockIdx.x, sp = blockIdx.y;
    const int tid = threadIdx.x;
    const int wv = tid >> 6, ln = tid & 63;
    const int i = sp * 4 + wv;           // row this wave owns
    const int j0 = ln * 2;

    float S0, S1;
    {
        float2 s2 = *(const float2*)(state_in + ((size_t)h * 128 + i) * 128 + j0);
        S0 = s2.x; S1 = s2.y;
    }

    __shared__ __align__(16) ushort lds_s[SNBP_][3072];
    const ushort* hbase = SFB + (size_t)h * 128 * 3072;

    auto STAGE = [&](int buf, int tp) {
        if (wv < 3) {
            const ushort* src = hbase + (size_t)(tp & 127) * 3072 + wv * 1024 + ln * 8;
            gload_lds16(src,       &lds_s[buf][wv * 1024]);
            gload_lds16(src + 512, &lds_s[buf][wv * 1024 + 512]);
        }
    };

#pragma unroll
    for (int d = 0; d < SDP_; d++) STAGE(d, d);

    float pend_y0 = 0.f, pend_y1 = 0.f;
    float r1c0 = 0.f, r1c1 = 0.f, bd1c = 0.f, vi1c = 0.f, gi1c = 0.f;
    for (int Io = 0; Io < 132; Io += 6) {
#pragma unroll
        for (int u = 0; u < 6; u++) {
            const int I = Io + u;
            if (I >= 128) break;
            const int bc = u;
            const int bs = (u + SDP_) % 6;

            if (wv < 3) {
                if (I < SDP_) asm volatile("s_waitcnt vmcnt(8)" ::: "memory");
                else          asm volatile("s_waitcnt vmcnt(16)" ::: "memory");
            }
            __builtin_amdgcn_s_barrier();
            __builtin_amdgcn_sched_barrier(0);
            asm volatile("" ::: "memory");

            if (ln == 0) {
                ushort* p0 = (I >= 1) ? (yb + (size_t)(2 * I - 2) * HN_ + h * 128 + i)
                                      : (dummy + tid);
                *p0 = (ushort)f2bf(pend_y0);
                ushort* p1 = (I >= 2) ? (yb + (size_t)(2 * I - 3) * HN_ + h * 128 + i)
                                      : (dummy + 256 + tid);
                *p1 = (ushort)f2bf(pend_y1);
            }

            STAGE(bs, I + SDP_);

            const ushort* L = lds_s[bc];
            const float* Lf = (const float*)L;
            float2 A0 = *(const float2*)(Lf + 0    + j0);
            float2 WA = *(const float2*)(Lf + 128  + j0);
            float2 WR = *(const float2*)(Lf + 256  + j0);
            float2 R1 = *(const float2*)(Lf + 384  + j0);
            float2 W2 = *(const float2*)(Lf + 512  + j0);
            float2 BW = *(const float2*)(Lf + 640  + j0);
            float2 KW = *(const float2*)(Lf + 768  + j0);
            float2 B1 = *(const float2*)(Lf + 896  + j0);
            float2 K1 = *(const float2*)(Lf + 1024 + j0);
            float vi0 = bf1(L[2304 + i]);
            float vi1 = bf1(L[2432 + i]);
            float gi0 = bf1(L[2560 + i]);
            float gi1 = bf1(L[2688 + i]);
            const float* Sc = Lf + 1408;
            float c1 = Sc[0], c2 = Sc[1], c3 = Sc[2], c4 = Sc[3];
            float bd0 = Sc[4], bd1 = Sc[5];

            float up = fmaf(S0, A0.x, S1 * A0.y);
            float pp = fmaf(S0, WA.x, S1 * WA.y);
            float yp = fmaf(S0, WR.x, S1 * WR.y);
            float op = fmaf(S0, r1c0, S1 * r1c1);
            float u_   = reduce64(up);
            float p_   = reduce64(pp);
            float yb0  = reduce64(yp);
            float od1  = reduce64(op);

            pend_y1 = fmaf(od1, 0.08838834764831845f, bd1c * vi1c) * gi1c;

            float sa0 = u_;
            float sa1 = fmaf(sa0, c1, fmaf(vi0, c2, p_));
            float od0 = fmaf(sa0, c3, fmaf(vi0, c4, yb0));
            pend_y0 = fmaf(od0, 0.08838834764831845f, bd0 * vi0) * gi0;

            S0 = fmaf(sa0, BW.x, S0 * W2.x);
            S0 = fmaf(vi0, KW.x, S0);
            S0 = fmaf(sa1, B1.x, S0);
            S0 = fmaf(vi1, K1.x, S0);
            S1 = fmaf(sa0, BW.y, S1 * W2.y);
            S1 = fmaf(vi0, KW.y, S1);
            S1 = fmaf(sa1, B1.y, S1);
            S1 = fmaf(vi1, K1.y, S1);

            r1c0 = R1.x; r1c1 = R1.y;
            bd1c = bd1; vi1c = vi1; gi1c = gi1;
        }
    }

    {
        float op = fmaf(S0, r1c0, S1 * r1c1);
        float od1 = reduce64(op);
        float cp1 = fmaf(od1, 0.08838834764831845f, bd1c * vi1c) * gi1c;
        if (ln == 0) {
            yb[(size_t)255 * HN_ + h * 128 + i] = (ushort)f2bf(cp1);
            yb[(size_t)254 * HN_ + h * 128 + i] = (ushort)f2bf(pend_y0);
            yb[(size_t)253 * HN_ + h * 128 + i] = (ushort)f2bf(pend_y1);
        }
    }

    float* pS = Sout + ((size_t)h * 128 + i) * 128 + j0;
    *(float2*)pS = make_float2(S0, S1);
}

// =====================================================================================
extern "C" void kernel_launch(void* const* d_in, const int* in_sizes, int n_in,
                              void* d_out, int out_size, void* d_ws, size_t ws_size,
                              hipStream_t stream) {
    const float* x_in   = (const float*)d_in[0];
    const float* vfirst = (const float*)d_in[1];
    const float* state  = (const float*)d_in[2];
    const int*   cpos   = (const int*)d_in[3];
    const float* w0 = (const float*)d_in[4];
    const float* w1 = (const float*)d_in[5];
    const float* w2 = (const float*)d_in[6];
    const float* a0 = (const float*)d_in[7];
    const float* a1 = (const float*)d_in[8];
    const float* a2 = (const float*)d_in[9];
    const float* v0 = (const float*)d_in[10];
    const float* v1 = (const float*)d_in[11];
    const float* v2 = (const float*)d_in[12];
    const float* g1 = (const float*)d_in[13];
    const float* g2 = (const float*)d_in[14];
    const float* r_k = (const float*)d_in[15];
    const float* R_ = (const float*)d_in[16];
    const float* K_ = (const float*)d_in[17];
    const float* V_ = (const float*)d_in[18];
    const float* O_ = (const float*)d_in[19];
    const float* Rb = (const float*)d_in[20];
    const float* Kb = (const float*)d_in[21];
    const float* Vb = (const float*)d_in[22];
    const float* ln_r = (const float*)d_in[23];
    const float* ln_k = (const float*)d_in[24];
    const float* ln1 = (const float*)d_in[25];
    const float* ln2 = (const float*)d_in[26];

    float* ws = (float*)d_ws;
    constexpr size_t OFF_XB   = 0;          // bf16 [256][4096]
    constexpr size_t OFF_COMB = 524288;     // f32 [256][6464]
    constexpr size_t OFF_WT   = 2179072;    // f32 [320][4096]
    constexpr size_t OFF_TCB  = 3489792;    // bf16 [256][320] = 40960 f32
    constexpr size_t OFF_WPRE = 3530752;    // bf16 [256][4096] = 524288 f32 slots used
    constexpr size_t OFF_APRE = 4579328;
    constexpr size_t OFF_VGPRE= 5627904;
    constexpr size_t OFF_G    = 6676480;
    constexpr size_t OFF_SF   = 7757824;    // pair stream: 32*128*6144B
    constexpr size_t OFF_DUM  = 14049280;   // dummy store sink
    constexpr size_t OFF_YB   = OFF_XB;     // alias (XB dead before scan)

    ushort* XB  = (ushort*)(ws + OFF_XB);
    float* COMB = ws + OFF_COMB;
    float* WT   = ws + OFF_WT;
    ushort* TCB = (ushort*)(ws + OFF_TCB);
    ushort* WPRE = (ushort*)(ws + OFF_WPRE);
    ushort* APRE = (ushort*)(ws + OFF_APRE);
    ushort* VGPRE= (ushort*)(ws + OFF_VGPRE);
    ushort* GARR = (ushort*)(ws + OFF_G);
    ushort* SFB = (ushort*)(ws + OFF_SF);
    ushort* DUM = (ushort*)(ws + OFF_DUM);
    ushort* YB  = (ushort*)(ws + OFF_YB);

    float* out = (float*)d_out;
    float* out0  = out;
    float* xlast = out + 1048576;
    float* Sfin  = out + 1052672;
    float* vfout = out + 1576960;
    float* xres  = out + 2625536;

    hipMemcpyAsync(vfout, vfirst, (size_t)1048576 * 4, hipMemcpyDeviceToDevice, stream);

    // rmsnorm also copies raw x_in into xres (removes a d2d memcpy)
    rmsnorm_k<<<T_, 256, 0, stream>>>(x_in, ln1, nullptr, XB, xlast, xres);

    wcat2_k<<<dim3(64, 5), 256, 0, stream>>>(w1, a1, v1, g1, WT);
    hipMemsetAsync(WT + (size_t)288 * 4096, 0, (size_t)32 * 4096 * 4, stream);
    init_comb_k<<<T_, 256, 0, stream>>>(Rb, Kb, Vb, COMB);

    gemm_rkvt<<<dim3(202, 4), 512, 0, stream>>>(XB, R_, K_, V_, WT, COMB);

    act_k<<<288, 256, 0, stream>>>(COMB, TCB);

    gemm_s2<<<dim3(128, 4), 512, 0, stream>>>(TCB, w2, a2, v2, g2, w0, a0, v0,
                                              WPRE, APRE, VGPRE, GARR);

    prep_k<<<dim3(128, 2), 256, 0, stream>>>(COMB, WPRE, APRE, VGPRE, vfirst, GARR,
                                             r_k, cpos, ln_r, ln_k, SFB);

    scan_k<<<dim3(32, 32), 256, 0, stream>>>(state, SFB, YB, Sfin, DUM);

    gemm_o<<<dim3(128, 4), 512, 0, stream>>>(YB, O_, xres);

    rmsnorm_k<<<T_, 256, 0, stream>>>(xres, ln2, out0, nullptr, nullptr, nullptr);
}